// Round 14
// baseline (164.994 us; speedup 1.0000x reference)
//
#include <hip/hip_runtime.h>

// Problem constants (from reference setup_inputs)
#define BB 4
#define CC 64
#define HH 56
#define WW 56
#define HW (HH*WW)

typedef unsigned short u16;
typedef unsigned int u32;
typedef __attribute__((ext_vector_type(8))) short bf16x8;
typedef __attribute__((ext_vector_type(4))) float f32x4;

__device__ __forceinline__ u16 f2bf(float f) {
    union { float f; unsigned u; } c; c.f = f;
    unsigned u = c.u;
    u = (u + 0x7FFFu + ((u >> 16) & 1u)) >> 16;   // RNE
    return (u16)u;
}
__device__ __forceinline__ float bf2f(u16 v) {
    union { unsigned u; float f; } c; c.u = ((unsigned)v) << 16;
    return c.f;
}
__device__ __forceinline__ float lo_f(u32 u) {   // bf16 pair -> lo fp32
    union { unsigned u; float f; } c; c.u = u << 16; return c.f;
}
__device__ __forceinline__ float hi_f(u32 u) {   // bf16 pair -> hi fp32
    union { unsigned u; float f; } c; c.u = u & 0xffff0000u; return c.f;
}

// ---------------------------------------------------------------------------
// Fused prep + input transpose in ONE launch.
// ---------------------------------------------------------------------------
#define R1 102400
#define R2 401408
#define R3 4096
#define R4 1600
#define R5 3136
#define TGRID (BB*(HW/64))          // 196
#define PREPN (R1+R2+R3+R4+R5)
__global__ __launch_bounds__(256)
void prep_tr_kernel(const float* __restrict__ x,
                    const float* __restrict__ ow1, const float* __restrict__ ow2,
                    const float* __restrict__ pw,  const float* __restrict__ dw1,
                    const float* __restrict__ dw2,
                    u16* __restrict__ xT,
                    u16* __restrict__ w2t1, u16* __restrict__ w2t2,
                    u16* __restrict__ pwT, float* __restrict__ dwT1,
                    float* __restrict__ dwT2) {
    __shared__ u16 tile[64][72];
    const int t = threadIdx.x;
    if (blockIdx.x < TGRID) {
        const int blk = blockIdx.x;
        const int b   = blk / (HW/64);
        const int p0  = (blk % (HW/64))*64;
        const int px  = t & 63, icq = t >> 6;
        const float* ip = x + ((size_t)b*CC + icq*16)*HW + p0 + px;
        #pragma unroll
        for (int i = 0; i < 16; ++i)
            tile[px][icq*16 + i] = f2bf(ip[(size_t)i*HW]);
        __syncthreads();
        const int px2 = t >> 2, g = t & 3;
        u16* op = xT + ((size_t)b*HW + p0 + px2)*64 + g*16;
        const uint4* s = (const uint4*)&tile[px2][g*16];
        ((uint4*)op)[0] = s[0];
        ((uint4*)op)[1] = s[1];
        return;
    }
    const int i = (blockIdx.x - TGRID)*256 + t;
    if (i < R1) {
        const int ic = i & 63, n = (i >> 6) & 63, tap = i >> 12;
        w2t1[i] = f2bf((n < 50) ? ow1[((size_t)n*64 + ic)*25 + tap] : 0.f);
    } else if (i < R1+R2) {
        const int j = i - R1;
        const int ic = j & 63, n = (j >> 6) & 127, tap = j >> 13;
        w2t2[j] = f2bf((n < 98) ? ow2[((size_t)n*64 + ic)*49 + tap] : 0.f);
    } else if (i < R1+R2+R3) {
        const int j = i - (R1+R2);
        pwT[j] = f2bf(pw[j]);
    } else if (i < R1+R2+R3+R4) {
        const int j = i - (R1+R2+R3);
        const int c = j & 63, k = j >> 6;
        dwT1[j] = dw1[c*25 + k];
    } else if (i < R1+R2+R3+R4+R5) {
        const int j = i - (R1+R2+R3+R4);
        const int c = j & 63, k = j >> 6;
        dwT2[j] = dw2[c*49 + k];
    }
}

__device__ __forceinline__ uint4 selz(bool v, uint4 a) {
    const uint4 z = make_uint4(0,0,0,0);
    return v ? a : z;
}

// ---------------------------------------------------------------------------
// LDS-staged MFMA implicit-GEMM conv (R10/R12-validated). NTW n-tiles per
// block (BROWS=16*NTW B rows staged, BRPT=BROWS/32 rows per thread).
// Transposed output off (B,HW,NPAD) fp32.
// ---------------------------------------------------------------------------
template<int K, int DIL, int PAD, int COUT, int NP, int NPAD, int NTW>
__global__ __launch_bounds__(256, 4)
void conv_mfma_lds_kernel(const u16* __restrict__ xT, const u16* __restrict__ w2t,
                          const float* __restrict__ bias, float* __restrict__ out) {
    constexpr int KK = K*K;
    constexpr int BROWS = 16*NTW;
    constexpr int BRPT  = (BROWS + 31)/32;        // B rows per thread
    __shared__ u16 Ab[2][64*64];
    __shared__ u16 Bb[2][BROWS*64];

    const int nm   = HW/64;                       // 49
    const int b    = blockIdx.x / nm;
    const int p0   = (blockIdx.x % nm)*64;
    const int nt0  = blockIdx.y;
    const int t    = threadIdx.x;
    const int wave = t >> 6;
    const int lane = t & 63;

    const int spx = t >> 3;                       // 0..31
    const int sc  = t & 7;                        // chunk 0..7
    const int pA  = p0 + spx;
    const int pB  = p0 + spx + 32;
    const int pyA = pA / WW, pxA = pA % WW;
    const int pyB = pB / WW, pxB = pB % WW;
    const u16* xb = xT + (size_t)b*HW*64;
    const int sslotA = ((sc + spx) & 7)*8;
    const int bn  = t >> 3;                       // 0..31
    const int bslot = ((sc + bn) & 7)*8;          // rr+32 has same slot
    const u16* wbase = w2t + (size_t)nt0*BROWS*64;

    const int r = lane & 15, quad = lane >> 4;
    const int mloc = wave*16 + r;
    const int arow = mloc*64;
    const int a0s = ((quad     + mloc) & 7)*8;
    const int a1s = ((quad + 4 + mloc) & 7)*8;
    const int b0s = ((quad     + r) & 7)*8;       // 16h % 8 == 0: same per h
    const int b1s = ((quad + 4 + r) & 7)*8;

    f32x4 acc[NTW];
    #pragma unroll
    for (int h = 0; h < NTW; ++h) acc[h] = (f32x4){0.f,0.f,0.f,0.f};
    const uint4 z4 = make_uint4(0,0,0,0);

    auto LD = [&](int tap, uint4& a0, uint4& a1, bool& va, bool& vb, uint4* bb) {
        const int dyy = (tap/K)*DIL - PAD;
        const int dxx = (tap%K)*DIL - PAD;
        const int off = dyy*WW + dxx;
        {
            const int yy = pyA + dyy, xx = pxA + dxx;
            va = ((unsigned)yy < (unsigned)HH) && ((unsigned)xx < (unsigned)WW);
            a0 = *(const uint4*)(xb + (size_t)(va ? (pA + off) : 0)*64 + sc*8);
        }
        {
            const int yy = pyB + dyy, xx = pxB + dxx;
            vb = ((unsigned)yy < (unsigned)HH) && ((unsigned)xx < (unsigned)WW);
            a1 = *(const uint4*)(xb + (size_t)(vb ? (pB + off) : 0)*64 + sc*8);
        }
        #pragma unroll
        for (int j = 0; j < BRPT; ++j) {
            const int rr = bn + 32*j;
            if (BROWS % 32 == 0 || rr < BROWS)
                bb[j] = *(const uint4*)(wbase + ((size_t)tap*NP + rr)*64 + sc*8);
        }
    };

    uint4 rA0 = z4, rA1 = z4, rB[BRPT];
    #pragma unroll
    for (int j = 0; j < BRPT; ++j) rB[j] = z4;
    bool v0 = false, v1 = false;
    LD(0, rA0, rA1, v0, v1, rB);

    #pragma unroll
    for (int tap = 0; tap < KK; ++tap) {
        uint4 nA0 = z4, nA1 = z4, nB[BRPT];
        #pragma unroll
        for (int j = 0; j < BRPT; ++j) nB[j] = z4;
        bool nv0 = false, nv1 = false;
        if (tap + 1 < KK) LD(tap + 1, nA0, nA1, nv0, nv1, nB);

        u16* A  = &Ab[tap & 1][0];
        u16* Bq = &Bb[tap & 1][0];
        *(uint4*)(A + spx*64      + sslotA) = selz(v0, rA0);
        *(uint4*)(A + (spx+32)*64 + sslotA) = selz(v1, rA1);
        #pragma unroll
        for (int j = 0; j < BRPT; ++j) {
            const int rr = bn + 32*j;
            if (BROWS % 32 == 0 || rr < BROWS)
                *(uint4*)(Bq + rr*64 + bslot) = rB[j];
        }
        __syncthreads();

        const bf16x8 av0 = *(const bf16x8*)(A + arow + a0s);
        const bf16x8 av1 = *(const bf16x8*)(A + arow + a1s);
        #pragma unroll
        for (int h = 0; h < NTW; ++h) {
            const int brow = (h*16 + r)*64;
            const bf16x8 bv0 = *(const bf16x8*)(Bq + brow + b0s);
            const bf16x8 bv1 = *(const bf16x8*)(Bq + brow + b1s);
            acc[h] = __builtin_amdgcn_mfma_f32_16x16x32_bf16(av0, bv0, acc[h], 0, 0, 0);
            acc[h] = __builtin_amdgcn_mfma_f32_16x16x32_bf16(av1, bv1, acc[h], 0, 0, 0);
        }

        rA0 = nA0; rA1 = nA1; v0 = nv0; v1 = nv1;
        #pragma unroll
        for (int j = 0; j < BRPT; ++j) rB[j] = nB[j];
    }

    #pragma unroll
    for (int h = 0; h < NTW; ++h) {
        const int n = nt0*BROWS + h*16 + r;
        if (n < COUT) {
            const float bv = bias[n];
            float* op = out + ((size_t)b*HW + p0 + wave*16 + quad*4)*NPAD + n;
            #pragma unroll
            for (int r2 = 0; r2 < 4; ++r2) op[(size_t)r2*NPAD] = acc[h][r2] + bv;
        }
    }
}

// ---------------------------------------------------------------------------
// Two-phase deform, 4 channels/lane. Wave = 4 px x 16 lanes x 4 ch (uint2
// corner loads: one wave-instr covers 4 pixel-rows). Block = 16 pixels.
// Phase 1 math unchanged. dw in LDS (float4/lane). XCD swizzle.
// ---------------------------------------------------------------------------
template<int K, int DIL, int PAD, int NPAD>
__global__ __launch_bounds__(256)
void deform_cl_kernel(const u16* __restrict__ inT, const float* __restrict__ offT,
                      const float* __restrict__ dwT, u16* __restrict__ outT) {
    constexpr int KK = K*K;
    __shared__ float4 swt[16][KK];
    __shared__ int4   sat[16][KK];
    __shared__ float  sdw[KK*64];

    const int t = threadIdx.x;
    const int nb8 = (BB*HW/16) >> 3;              // 98
    const int blk0 = blockIdx.x;
    const int blk = (blk0 & 7)*nb8 + (blk0 >> 3); // XCD-contiguous pixels
    const int p0 = blk*16;
    const int b  = p0 / HW;                       // 16 | HW -> same batch
    const int pl0 = p0 - b*HW;

    for (int i = t; i < KK*64; i += 256) sdw[i] = dwT[i];

    for (int i = t; i < 16*KK; i += 256) {
        const int pix = i / KK, k = i - pix*KK;
        const int pl  = pl0 + pix;
        const int h = pl / WW, w = pl % WW;
        const float* orow = offT + ((size_t)b*HW + pl)*NPAD;
        const float dy = orow[2*k];
        const float dx = orow[2*k+1];
        const float py = (float)(h + (k/K)*DIL - PAD) + dy;
        const float px = (float)(w + (k%K)*DIL - PAD) + dx;
        const float y0f = floorf(py), x0f = floorf(px);
        const float wy1 = py - y0f,  wx1 = px - x0f;
        const float wy0 = 1.f - wy1, wx0 = 1.f - wx1;
        const int y0 = (int)y0f, x0 = (int)x0f;

        const int y0c = min(max(y0,   0), HH-1);
        const int y1c = min(max(y0+1, 0), HH-1);
        const int x0c = min(max(x0,   0), WW-1);
        const int x1c = min(max(x0+1, 0), WW-1);
        const float gy0 = wy0 * ((y0   >= 0 && y0   < HH) ? 1.f : 0.f);
        const float gy1 = wy1 * ((y0+1 >= 0 && y0+1 < HH) ? 1.f : 0.f);
        const float gx0 = wx0 * ((x0   >= 0 && x0   < WW) ? 1.f : 0.f);
        const float gx1 = wx1 * ((x0+1 >= 0 && x0+1 < WW) ? 1.f : 0.f);

        swt[pix][k] = make_float4(gy0*gx0, gy0*gx1, gy1*gx0, gy1*gx1);
        const int r0 = y0c*WW, r1 = y1c*WW;
        sat[pix][k] = make_int4((r0 + x0c) << 7, (r0 + x1c) << 7,
                                (r1 + x0c) << 7, (r1 + x1c) << 7);
    }
    __syncthreads();

    const int wave = t >> 6, lane = t & 63;
    const int pixl = 4*wave + (lane >> 4);        // 0..15 (quarter-wave = px)
    const int chq  = lane & 15;                   // channel quad 0..15
    const char* ib = (const char*)(inT + (size_t)b*HW*64) + chq*8;

    float a0 = 0.f, a1 = 0.f, a2 = 0.f, a3 = 0.f;
    #pragma unroll 7
    for (int k = 0; k < KK; ++k) {
        const float4 wv = swt[pixl][k];
        const int4   av = sat[pixl][k];
        const uint2 c00 = *(const uint2*)(ib + av.x);
        const uint2 c01 = *(const uint2*)(ib + av.y);
        const uint2 c10 = *(const uint2*)(ib + av.z);
        const uint2 c11 = *(const uint2*)(ib + av.w);
        const float s0 = lo_f(c00.x)*wv.x + lo_f(c01.x)*wv.y + lo_f(c10.x)*wv.z + lo_f(c11.x)*wv.w;
        const float s1 = hi_f(c00.x)*wv.x + hi_f(c01.x)*wv.y + hi_f(c10.x)*wv.z + hi_f(c11.x)*wv.w;
        const float s2 = lo_f(c00.y)*wv.x + lo_f(c01.y)*wv.y + lo_f(c10.y)*wv.z + lo_f(c11.y)*wv.w;
        const float s3 = hi_f(c00.y)*wv.x + hi_f(c01.y)*wv.y + hi_f(c10.y)*wv.z + hi_f(c11.y)*wv.w;
        const float4 dw4 = *(const float4*)&sdw[k*64 + 4*chq];
        a0 += s0 * dw4.x;
        a1 += s1 * dw4.y;
        a2 += s2 * dw4.z;
        a3 += s3 * dw4.w;
    }
    uint2 o;
    o.x = (u32)f2bf(a0) | ((u32)f2bf(a1) << 16);
    o.y = (u32)f2bf(a2) | ((u32)f2bf(a3) << 16);
    *(uint2*)((char*)outT + (size_t)(p0 + pixl)*128 + chq*8) = o;
}

// ---------------------------------------------------------------------------
// Pointwise 1x1 via MFMA + fused residual multiply; wave = 16 px x 1 n-tile.
// ---------------------------------------------------------------------------
__global__ __launch_bounds__(256)
void pw_mfma_kernel(const u16* __restrict__ a2T, const u16* __restrict__ pwT,
                    const float* __restrict__ pb, const float* __restrict__ x,
                    float* __restrict__ out) {
    const int nm = HW/64;
    const int b  = blockIdx.x / nm;
    const int p0 = (blockIdx.x % nm)*64 + (threadIdx.x >> 6)*16;
    const int nt = blockIdx.y;
    const int lane = threadIdx.x & 63;
    const int r = lane & 15, quad = lane >> 4;

    const u16* ap = a2T + ((size_t)b*HW + p0 + r)*64 + quad*8;
    f32x4 acc = (f32x4){0.f,0.f,0.f,0.f};
    #pragma unroll
    for (int ks = 0; ks < 2; ++ks) {
        const bf16x8 av = *(const bf16x8*)(ap + ks*32);
        const bf16x8 bv = *(const bf16x8*)(pwT + ((size_t)(nt*16 + r))*64 + ks*32 + quad*8);
        acc = __builtin_amdgcn_mfma_f32_16x16x32_bf16(av, bv, acc, 0, 0, 0);
    }

    const int n = nt*16 + r;
    const float bv = pb[n];
    const size_t base = ((size_t)b*CC + n)*HW + p0 + quad*4;
    #pragma unroll
    for (int r2 = 0; r2 < 4; ++r2)
        out[base + r2] = x[base + r2] * (acc[r2] + bv);
}

// ======================= fallback fp32 kernels (low ws) =====================
template<int K, int DIL, int PAD, int COUT, int OCB>
__global__ __launch_bounds__(256)
void off_conv_sg_kernel(const float* __restrict__ in, const float* __restrict__ wgt,
                        const float* __restrict__ bias, float* __restrict__ out) {
    constexpr int KK = K*K;
    const int nOB = COUT / OCB;
    const int b   = blockIdx.x / nOB;
    const int oc0 = (blockIdx.x % nOB) * OCB;
    const int x   = threadIdx.x;
    const int h   = blockIdx.y*4 + threadIdx.y;

    float acc[OCB];
    #pragma unroll
    for (int o = 0; o < OCB; ++o) acc[o] = bias[oc0+o];

    const float* inb = in + (size_t)b*CC*HW;
    const float* wb  = wgt + (size_t)oc0*CC*KK;

    for (int ic = 0; ic < CC; ++ic) {
        const float* inp = inb + ic*HW;
        const float* wp  = wb + ic*KK;
        #pragma unroll
        for (int ky = 0; ky < K; ++ky) {
            const int  y  = h + ky*DIL - PAD;
            const bool yv = (y >= 0) && (y < HH);
            const int  yc = yv ? y : 0;
            const float* row = inp + yc*WW;
            #pragma unroll
            for (int kx = 0; kx < K; ++kx) {
                const int  xx = x + kx*DIL - PAD;
                const bool v  = yv && (xx >= 0) && (xx < WW);
                const int  xc = (xx < 0) ? 0 : ((xx >= WW) ? (WW-1) : xx);
                float val = row[xc];
                val = v ? val : 0.f;
                const int t = ky*K + kx;
                #pragma unroll
                for (int o = 0; o < OCB; ++o)
                    acc[o] += wp[(size_t)o*CC*KK + t] * val;
            }
        }
    }

    if (x >= WW) return;
    #pragma unroll
    for (int o = 0; o < OCB; ++o)
        out[((size_t)b*COUT + oc0 + o)*HW + h*WW + x] = acc[o];
}

template<int K, int DIL, int PAD>
__global__ __launch_bounds__(64)
void deform_dw_full_kernel(const float* __restrict__ in, const float* __restrict__ off,
                           const float* __restrict__ dw, float* __restrict__ out) {
    constexpr int KK = K*K;
    const int idx = blockIdx.x*64 + threadIdx.x;
    const int x = idx % WW;
    const int h = (idx / WW) % HH;
    const int c = (idx / HW) % CC;
    const int b = idx / (CC*HW);

    const float* inp  = in  + ((size_t)b*CC + c)*HW;
    const float* offp = off + (size_t)b*(2*KK)*HW + h*WW + x;
    const float* dwp  = dw  + c*KK;

    float acc = 0.f;
    #pragma unroll 7
    for (int k = 0; k < KK; ++k) {
        const float dy = offp[(2*k  )*HW];
        const float dx = offp[(2*k+1)*HW];
        const float py = (float)(h + (k/K)*DIL - PAD) + dy;
        const float px = (float)(x + (k%K)*DIL - PAD) + dx;
        const float y0f = floorf(py), x0f = floorf(px);
        const float wy1 = py - y0f,  wx1 = px - x0f;
        const float wy0 = 1.f - wy1, wx0 = 1.f - wx1;
        const int y0 = (int)y0f, x0 = (int)x0f;

        const int y0c = min(max(y0,   0), HH-1);
        const int y1c = min(max(y0+1, 0), HH-1);
        const int x0c = min(max(x0,   0), WW-1);
        const int x1c = min(max(x0+1, 0), WW-1);
        const float my0 = (y0   >= 0 && y0   < HH) ? 1.f : 0.f;
        const float my1 = (y0+1 >= 0 && y0+1 < HH) ? 1.f : 0.f;
        const float mx0 = (x0   >= 0 && x0   < WW) ? 1.f : 0.f;
        const float mx1 = (x0+1 >= 0 && x0+1 < WW) ? 1.f : 0.f;

        const float v00 = inp[y0c*WW + x0c];
        const float v01 = inp[y0c*WW + x1c];
        const float v10 = inp[y1c*WW + x0c];
        const float v11 = inp[y1c*WW + x1c];

        const float gx0 = wx0*mx0, gx1 = wx1*mx1;
        const float s = (v00*gx0 + v01*gx1) * (wy0*my0)
                      + (v10*gx0 + v11*gx1) * (wy1*my1);
        acc += s * dwp[k];
    }
    out[idx] = acc;
}

__global__ __launch_bounds__(256)
void pw_mul_kernel(const float* __restrict__ x, const float* __restrict__ a2,
                   const float* __restrict__ pw, const float* __restrict__ pb,
                   float* __restrict__ out) {
    constexpr int HW4 = HW/4;
    const int t = blockIdx.x*256 + threadIdx.x;
    if (t >= BB*CC*HW4) return;
    const int sp4 = t % HW4;
    const int oc  = (t / HW4) % CC;
    const int b   = t / (CC*HW4);

    const float4* ap = (const float4*)(a2 + (size_t)b*CC*HW) + sp4;
    const float4* wp4 = (const float4*)(pw + oc*CC);
    const float pbv = pb[oc];
    float4 acc = make_float4(pbv, pbv, pbv, pbv);
    #pragma unroll 4
    for (int ic4 = 0; ic4 < CC/4; ++ic4) {
        const float4 w = wp4[ic4];
        float4 a0 = ap[(ic4*4+0)*HW4];
        float4 a1 = ap[(ic4*4+1)*HW4];
        float4 a2v = ap[(ic4*4+2)*HW4];
        float4 a3 = ap[(ic4*4+3)*HW4];
        acc.x += w.x*a0.x + w.y*a1.x + w.z*a2v.x + w.w*a3.x;
        acc.y += w.x*a0.y + w.y*a1.y + w.z*a2v.y + w.w*a3.y;
        acc.z += w.x*a0.z + w.y*a1.z + w.z*a2v.z + w.w*a3.z;
        acc.w += w.x*a0.w + w.y*a1.w + w.z*a2v.w + w.w*a3.w;
    }
    const float4 xv = ((const float4*)x)[t];
    float4 r;
    r.x = xv.x*acc.x; r.y = xv.y*acc.y; r.z = xv.z*acc.z; r.w = xv.w*acc.w;
    ((float4*)out)[t] = r;
}

extern "C" void kernel_launch(void* const* d_in, const int* in_sizes, int n_in,
                              void* d_out, int out_size, void* d_ws, size_t ws_size,
                              hipStream_t stream) {
    const float* x      = (const float*)d_in[0];
    const float* off_w1 = (const float*)d_in[1];
    const float* off_b1 = (const float*)d_in[2];
    const float* dw_w1  = (const float*)d_in[3];
    const float* off_w2 = (const float*)d_in[4];
    const float* off_b2 = (const float*)d_in[5];
    const float* dw_w2  = (const float*)d_in[6];
    const float* pw_w   = (const float*)d_in[7];
    const float* pw_b   = (const float*)d_in[8];
    float* out = (float*)d_out;

    const size_t nF    = (size_t)BB*CC*HW;
    const size_t attnB = nF*sizeof(float);
    const size_t off2B = (size_t)BB*98*HW*sizeof(float);   // fallback layout
    const size_t offTB = (size_t)BB*HW*112*sizeof(float);  // transposed offsets
    const size_t chB   = (size_t)BB*HW*64*sizeof(u16);
    char* ws = (char*)d_ws;

    const int n    = (int)nF;
    const int dbl  = n/64;
    const int pbl  = (n/4 + 255)/256;
    dim3 cblk(64,4);
    dim3 rgrd1(BB*(50/5), HH/4);
    dim3 rgrd2(BB*(98/7), HH/4);
    dim3 cgrd1(TGRID, 2);                    // conv1: NTW=2, 64 n
    dim3 cgrd2(TGRID, 2);                    // conv2: NTW=4, 128 n (padded)
    dim3 pgrd(TGRID, 4);                     // pw
    const int dgrid = BB*HW/16;              // 784 (16 pixels per block)

    const size_t oOFF  = 0;
    const size_t oXT   = oOFF + offTB;
    const size_t oA1T  = oXT  + chB;
    const size_t oA2T  = oA1T + chB;
    const size_t oW1   = oA2T + chB;
    const size_t oW2   = oW1  + (size_t)R1*2;
    const size_t oPWT  = oW2  + (size_t)R2*2;
    const size_t oDW1  = oPWT + (size_t)R3*2;
    const size_t oDW2  = oDW1 + (size_t)R4*4;
    const size_t TOT   = oDW2 + (size_t)R5*4;   // ~11.47 MB

    if (ws_size >= TOT) {
        float* off_buf = (float*)(ws + oOFF);
        u16*   xT      = (u16*)(ws + oXT);
        u16*   a1T     = (u16*)(ws + oA1T);
        u16*   a2T     = (u16*)(ws + oA2T);
        u16*   w2t1    = (u16*)(ws + oW1);
        u16*   w2t2    = (u16*)(ws + oW2);
        u16*   pwT     = (u16*)(ws + oPWT);
        float* dwT1    = (float*)(ws + oDW1);
        float* dwT2    = (float*)(ws + oDW2);

        prep_tr_kernel<<<TGRID + (PREPN+255)/256, 256, 0, stream>>>(
            x, off_w1, off_w2, pw_w, dw_w1, dw_w2,
            xT, w2t1, w2t2, pwT, dwT1, dwT2);

        conv_mfma_lds_kernel<5,1,2,50,64,64,2><<<cgrd1, 256, 0, stream>>>(xT, w2t1, off_b1, off_buf);
        deform_cl_kernel<5,1,2,64><<<dgrid, 256, 0, stream>>>(xT, off_buf, dwT1, a1T);

        conv_mfma_lds_kernel<7,3,9,98,128,112,4><<<cgrd2, 256, 0, stream>>>(a1T, w2t2, off_b2, off_buf);
        deform_cl_kernel<7,3,9,112><<<dgrid, 256, 0, stream>>>(a1T, off_buf, dwT2, a2T);

        pw_mfma_kernel<<<pgrd, 256, 0, stream>>>(a2T, pwT, pw_b, x, out);
    } else if (ws_size >= off2B + attnB) {
        float* off_buf = (float*)ws;
        float* attn1   = (float*)d_out;
        float* attn2   = (float*)(ws + off2B);
        off_conv_sg_kernel<5,1,2,50,5><<<rgrd1, cblk, 0, stream>>>(x, off_w1, off_b1, off_buf);
        deform_dw_full_kernel<5,1,2><<<dbl, 64, 0, stream>>>(x, off_buf, dw_w1, attn1);
        off_conv_sg_kernel<7,3,9,98,7><<<rgrd2, cblk, 0, stream>>>(attn1, off_w2, off_b2, off_buf);
        deform_dw_full_kernel<7,3,9><<<dbl, 64, 0, stream>>>(attn1, off_buf, dw_w2, attn2);
        pw_mul_kernel<<<pbl, 256, 0, stream>>>(x, attn2, pw_w, pw_b, out);
    } else {
        float* attn1 = (float*)d_out;
        float* attn2 = (float*)ws;
        float* off1  = (float*)ws;
        off_conv_sg_kernel<5,1,2,50,5><<<rgrd1, cblk, 0, stream>>>(x, off_w1, off_b1, off1);
        deform_dw_full_kernel<5,1,2><<<dbl, 64, 0, stream>>>(x, off1, dw_w1, attn1);
        float* off2 = (float*)(ws + attnB);
        off_conv_sg_kernel<7,3,9,98,7><<<rgrd2, cblk, 0, stream>>>(attn1, off_w2, off_b2, off2);
        deform_dw_full_kernel<7,3,9><<<dbl, 64, 0, stream>>>(attn1, off2, dw_w2, attn2);
        pw_mul_kernel<<<pbl, 256, 0, stream>>>(x, attn2, pw_w, pw_b, out);
    }
}